// Round 7
// baseline (52.204 us; speedup 1.0000x reference)
//
#include <hip/hip_runtime.h>
#include <hip/hip_bf16.h>

// ShuffleNet fused block-MLP, MI355X (gfx950).  R7: split kept; k1 rebuilt in
// k2's proven shape: small register state, many short waves, all loads
// independent, explicit named x double-buffer (no dynamic-indexed arrays).
// x:(8192,1024) f32; w1:(16,256,64); b1:(4096); w2:(16,64,256); b2:(1024); y f32.
//   h[b,n,o] = sum_i x[b,n*64+i]*w1[n,o,i];  shuffled j = o*16+n
//   g = gelu(h+b1);  y[b,np*64+o'] = sum_{i'} g[b,np*256+i']*w2[np,o',i'] + b2
//   i' = n*16 + ohi  with  o = np*16 + ohi.
// G layout (shorts): G[rt][np][n][row16][ohi16]; strides 65536/4096/256/16/1.
// k1: wave = (n, np-quarter=wv, rtg); 4 np resident (40 VGPR), streams 8
//     rowtiles; x prefetched one tile ahead into named regs. 1024 WGs.
// k2: unchanged since R4 (~11.5us, ~roofline for its traffic).

typedef __attribute__((ext_vector_type(8))) short  short8;   // 8 bf16 = 4 VGPR
typedef __attribute__((ext_vector_type(4))) short  short4v;
typedef __attribute__((ext_vector_type(4))) float  floatx4;

__device__ __forceinline__ short f2bf(float f) {
  union { __hip_bfloat16 h; short s; } u;
  u.h = __float2bfloat16(f);
  return u.s;
}
__device__ __forceinline__ float bf2f(short s) {
  union { float f; unsigned u; } uu;
  uu.u = ((unsigned)(unsigned short)s) << 16;
  return uu.f;
}

// gelu(v) ~= v * sigmoid(1.5957691*(v + 0.044715 v^3)), exp2-folded:
// g = v * rcp(1 + exp2(v*(-2.3020807 - 0.1029375*v*v)))   (5 VALU + 2 TRANS)
__device__ __forceinline__ float gelu_f(float v) {
  float m = v * v;
  float c = fmaf(-0.1029375f, m, -2.3020807f);
  float z = v * c;
  float e = __builtin_amdgcn_exp2f(z);
  return v * __builtin_amdgcn_rcpf(1.0f + e);
}

// ---- one pack kernel: w1 frags | w2 frags | b1 frags (bf16) ----
// w1 frag (n,np,ks): lane l elem e = w1[n][np*16+(l&15)][ks*32+(l>>4)*8+e]
// w2 frag (np,ks,ot): lane l elem e: k=ks*32+(l>>4)*8+e; value =
//                     w2[np][ot*16+(l&15)][(k&15)*16+(k>>4)]
// b1 frag (n,np): lane l reg r = bf16(b1[(np*16+(l>>4)*4+r)*16+n])
__global__ void pack_k(const float* __restrict__ w1, const float* __restrict__ w2,
                       const float* __restrict__ b1, short* __restrict__ w1p,
                       short* __restrict__ w2p, short* __restrict__ b1p) {
  const int t = blockIdx.x * blockDim.x + threadIdx.x;  // 160*512 = 81920
  const int lane = t & 63;
  const int lhi = lane >> 4;
  if (t < 32768) {  // w1
    const int ks = (t >> 6) & 1, np = (t >> 7) & 15, n = (t >> 11) & 15;
    const float* src = w1 + ((size_t)(n * 256 + np * 16 + (lane & 15)) * 64 + ks * 32 + lhi * 8);
    short8 f;
#pragma unroll
    for (int e = 0; e < 8; ++e) f[e] = f2bf(src[e]);
    *(short8*)(w1p + (size_t)t * 8) = f;
  } else if (t < 65536) {  // w2
    const int t2 = t - 32768;
    const int ot = (t2 >> 6) & 3, ks = (t2 >> 8) & 7, np = (t2 >> 11) & 15;
    const int op = ot * 16 + (lane & 15);
    short8 f;
#pragma unroll
    for (int e = 0; e < 8; ++e) {
      const int k = ks * 32 + lhi * 8 + e;
      f[e] = f2bf(w2[(size_t)(np * 64 + op) * 256 + (k & 15) * 16 + (k >> 4)]);
    }
    *(short8*)(w2p + (size_t)t2 * 8) = f;
  } else {  // b1 -> bf16 frags
    const int t3 = t - 65536;  // 16384
    const int np = (t3 >> 6) & 15, n = (t3 >> 10) & 15;
    short4v b;
#pragma unroll
    for (int r = 0; r < 4; ++r) b[r] = f2bf(b1[(np * 16 + lhi * 4 + r) * 16 + n]);
    *(short4v*)(b1p + (size_t)((n * 16 + np) * 64 + lane) * 4) = b;
  }
}

// ---- K1: x -> g. 1024 WGs x 256 thr; wave = (n = b>>6, q = wv, rtg = b&63).
// 4 np resident; 8 rowtiles streamed with named 2-buffer x pipeline. ----
__global__ __launch_bounds__(256, 4) void k1_gemm1(
    const float* __restrict__ x, const short* __restrict__ w1p,
    const short* __restrict__ b1p, short* __restrict__ G) {
  const int tid = threadIdx.x;
  const int wv = tid >> 6, lane = tid & 63;
  const int l15 = lane & 15, lhi = lane >> 4;
  const int b   = blockIdx.x;      // 0..1023
  const int n   = b >> 6;          // 0..15
  const int rtg = b & 63;          // rt = rtg*8 + r
  const int np0 = wv * 4;

  // resident: 4 np of weights (32 VGPR) + bf16 bias (8 VGPR)
  short8  wf[4][2];
  short4v bv[4];
#pragma unroll
  for (int j = 0; j < 4; ++j) {
    const int np = np0 + j;
    wf[j][0] = *(const short8*)(w1p + (size_t)(((n * 16 + np) * 2 + 0) * 64 + lane) * 8);
    wf[j][1] = *(const short8*)(w1p + (size_t)(((n * 16 + np) * 2 + 1) * 64 + lane) * 8);
    bv[j]    = *(const short4v*)(b1p + (size_t)((n * 16 + np) * 64 + lane) * 4);
  }

  const float* xb = x + (size_t)(rtg * 8 * 16 + l15) * 1024 + n * 64 + lhi * 8;
  const size_t rstep = (size_t)16 * 1024;   // one rowtile = 16 rows

#define XLOAD(B0, B1, B2, B3, r)                      \
  {                                                   \
    const float* px_ = xb + (size_t)(r) * rstep;      \
    B0 = *(const floatx4*)px_;                        \
    B1 = *(const floatx4*)(px_ + 4);                  \
    B2 = *(const floatx4*)(px_ + 32);                 \
    B3 = *(const floatx4*)(px_ + 36);                 \
  }

#define COMPUTE(B0, B1, B2, B3, r)                                            \
  {                                                                           \
    short8 xf0, xf1;                                                          \
    _Pragma("unroll")                                                         \
    for (int e = 0; e < 4; ++e) {                                             \
      xf0[e] = f2bf(B0[e]); xf0[e + 4] = f2bf(B1[e]);                         \
      xf1[e] = f2bf(B2[e]); xf1[e + 4] = f2bf(B3[e]);                         \
    }                                                                         \
    short* gb_ = G + (size_t)(rtg * 8 + (r)) * 65536 + n * 256 + l15 * 16 + lhi * 4; \
    _Pragma("unroll")                                                         \
    for (int j = 0; j < 4; ++j) {                                             \
      floatx4 acc = {0.f, 0.f, 0.f, 0.f};                                     \
      acc = __builtin_amdgcn_mfma_f32_16x16x32_bf16(wf[j][0], xf0, acc, 0, 0, 0); \
      acc = __builtin_amdgcn_mfma_f32_16x16x32_bf16(wf[j][1], xf1, acc, 0, 0, 0); \
      short4v hv;                                                             \
      _Pragma("unroll")                                                       \
      for (int e = 0; e < 4; ++e)                                             \
        hv[e] = f2bf(gelu_f(acc[e] + bf2f(bv[j][e])));                        \
      *(short4v*)(gb_ + (size_t)(np0 + j) * 4096) = hv;                       \
    }                                                                         \
  }

  floatx4 A0, A1, A2, A3, B0, B1, B2, B3;
  XLOAD(A0, A1, A2, A3, 0)
#pragma unroll
  for (int rp = 0; rp < 4; ++rp) {
    XLOAD(B0, B1, B2, B3, rp * 2 + 1)     // prefetch odd tile
    COMPUTE(A0, A1, A2, A3, rp * 2)       // compute even tile
    if (rp < 3) XLOAD(A0, A1, A2, A3, rp * 2 + 2)  // prefetch next even
    COMPUTE(B0, B1, B2, B3, rp * 2 + 1)   // compute odd tile
  }
#undef XLOAD
#undef COMPUTE
}

// ---- K2: g -> y, 2048 WGs x 256 thr, wave = (rt, np)  [unchanged from R4] ----
__global__ __launch_bounds__(256, 4) void k2_gemm2(
    const short* __restrict__ G, const short* __restrict__ w2p,
    const float* __restrict__ b2, float* __restrict__ y) {
  const int tid = threadIdx.x;
  const int wv = tid >> 6, lane = tid & 63;
  const int l15 = lane & 15, lhi = lane >> 4;
  const int rt = blockIdx.x >> 2;
  const int np = (blockIdx.x & 3) * 4 + wv;

  const short* ab = G + (size_t)(rt * 16 + np) * 4096 + (lhi >> 1) * 256 + l15 * 16 + (lhi & 1) * 8;
  short8 af[8];
#pragma unroll
  for (int ks = 0; ks < 8; ++ks)
    af[ks] = *(const short8*)(ab + ks * 512);

#pragma unroll
  for (int ot = 0; ot < 4; ++ot) {
    floatx4 a0 = {0.f, 0.f, 0.f, 0.f}, a1 = {0.f, 0.f, 0.f, 0.f};
#pragma unroll
    for (int ks = 0; ks < 8; ks += 2) {
      short8 b0  = *(const short8*)(w2p + (size_t)(((np * 8 + ks) * 4 + ot) * 64 + lane) * 8);
      short8 b1f = *(const short8*)(w2p + (size_t)(((np * 8 + ks + 1) * 4 + ot) * 64 + lane) * 8);
      a0 = __builtin_amdgcn_mfma_f32_16x16x32_bf16(af[ks], b0, a0, 0, 0, 0);
      a1 = __builtin_amdgcn_mfma_f32_16x16x32_bf16(af[ks + 1], b1f, a1, 0, 0, 0);
    }
    const int col = np * 64 + ot * 16 + l15;
    const float bb = b2[col];
    float* py = y + (size_t)(rt * 16 + lhi * 4) * 1024 + col;
#pragma unroll
    for (int r = 0; r < 4; ++r)
      py[(size_t)r * 1024] = a0[r] + a1[r] + bb;
  }
}

extern "C" void kernel_launch(void* const* d_in, const int* in_sizes, int n_in,
                              void* d_out, int out_size, void* d_ws, size_t ws_size,
                              hipStream_t stream) {
  const float* x  = (const float*)d_in[0];
  const float* w1 = (const float*)d_in[1];
  const float* b1 = (const float*)d_in[2];
  const float* w2 = (const float*)d_in[3];
  const float* b2 = (const float*)d_in[4];
  float* y = (float*)d_out;

  short* w1p = (short*)d_ws;               // 512 KB
  short* w2p = w1p + 16 * 256 * 64;        // 512 KB
  short* b1p = w2p + 16 * 256 * 64;        // 128 KB
  short* G   = b1p + 16 * 16 * 64 * 4;     // 64 MB

  pack_k<<<160, 512, 0, stream>>>(w1, w2, b1, w1p, w2p, b1p);
  k1_gemm1<<<1024, 256, 0, stream>>>(x, w1p, b1p, G);
  k2_gemm2<<<2048, 256, 0, stream>>>(G, w2p, b2, y);
}

// Round 8
// 49.360 us; speedup vs baseline: 1.0576x; 1.0576x over previous
//
#include <hip/hip_runtime.h>
#include <hip/hip_bf16.h>

// ShuffleNet fused block-MLP, MI355X (gfx950).  R8: k1 with cooperative LDS
// staging of x (kills the 16-way fragment gather that capped R4/R6/R7 k1 at
// ~39us). k2 unchanged (~roofline).
// x:(8192,1024) f32; w1:(16,256,64); b1:(4096); w2:(16,64,256); b2:(1024); y f32.
//   h[b,n,o] = sum_i x[b,n*64+i]*w1[n,o,i];  shuffled j = o*16+n
//   g = gelu(h+b1);  y[b,np*64+o'] = sum_{i'} g[b,np*256+i']*w2[np,o',i'] + b2
//   i' = n*16 + ohi  with  o = np*16 + ohi.
// G layout (shorts): G[rt][np][n][row16][ohi16]; strides 65536/4096/256/16/1.
// k1 WG = (n = b>>6, rtg = b&63): slab x[rtg*128..+128][n*64..+64) staged to
// LDS bf16 (coalesced 256B-row loads), 1 barrier, then 8 rowtiles of pure
// {ds_read_b128, MFMA, gelu, contiguous 512B stores}. Wave wv owns np-quarter.

typedef __attribute__((ext_vector_type(8))) short  short8;   // 8 bf16 = 4 VGPR
typedef __attribute__((ext_vector_type(4))) short  short4v;
typedef __attribute__((ext_vector_type(4))) float  floatx4;

#define XPITCH 72   // shorts per staged row (144B: 16B-aligned, bank-rotating)

__device__ __forceinline__ short f2bf(float f) {
  union { __hip_bfloat16 h; short s; } u;
  u.h = __float2bfloat16(f);
  return u.s;
}
__device__ __forceinline__ float bf2f(short s) {
  union { float f; unsigned u; } uu;
  uu.u = ((unsigned)(unsigned short)s) << 16;
  return uu.f;
}

// gelu(v) ~= v * sigmoid(1.5957691*(v + 0.044715 v^3)), exp2-folded:
// g = v * rcp(1 + exp2(v*(-2.3020807 - 0.1029375*v*v)))   (5 VALU + 2 TRANS)
__device__ __forceinline__ float gelu_f(float v) {
  float m = v * v;
  float c = fmaf(-0.1029375f, m, -2.3020807f);
  float z = v * c;
  float e = __builtin_amdgcn_exp2f(z);
  return v * __builtin_amdgcn_rcpf(1.0f + e);
}

// ---- one pack kernel: w1 frags | w2 frags | b1 frags (bf16) ----
// w1 frag (n,np,ks): lane l elem e = w1[n][np*16+(l&15)][ks*32+(l>>4)*8+e]
// w2 frag (np,ks,ot): lane l elem e: k=ks*32+(l>>4)*8+e; value =
//                     w2[np][ot*16+(l&15)][(k&15)*16+(k>>4)]
// b1 frag (n,np): lane l reg r = bf16(b1[(np*16+(l>>4)*4+r)*16+n])
__global__ void pack_k(const float* __restrict__ w1, const float* __restrict__ w2,
                       const float* __restrict__ b1, short* __restrict__ w1p,
                       short* __restrict__ w2p, short* __restrict__ b1p) {
  const int t = blockIdx.x * blockDim.x + threadIdx.x;  // 160*512 = 81920
  const int lane = t & 63;
  const int lhi = lane >> 4;
  if (t < 32768) {  // w1
    const int ks = (t >> 6) & 1, np = (t >> 7) & 15, n = (t >> 11) & 15;
    const float* src = w1 + ((size_t)(n * 256 + np * 16 + (lane & 15)) * 64 + ks * 32 + lhi * 8);
    short8 f;
#pragma unroll
    for (int e = 0; e < 8; ++e) f[e] = f2bf(src[e]);
    *(short8*)(w1p + (size_t)t * 8) = f;
  } else if (t < 65536) {  // w2
    const int t2 = t - 32768;
    const int ot = (t2 >> 6) & 3, ks = (t2 >> 8) & 7, np = (t2 >> 11) & 15;
    const int op = ot * 16 + (lane & 15);
    short8 f;
#pragma unroll
    for (int e = 0; e < 8; ++e) {
      const int k = ks * 32 + lhi * 8 + e;
      f[e] = f2bf(w2[(size_t)(np * 64 + op) * 256 + (k & 15) * 16 + (k >> 4)]);
    }
    *(short8*)(w2p + (size_t)t2 * 8) = f;
  } else {  // b1 -> bf16 frags
    const int t3 = t - 65536;  // 16384
    const int np = (t3 >> 6) & 15, n = (t3 >> 10) & 15;
    short4v b;
#pragma unroll
    for (int r = 0; r < 4; ++r) b[r] = f2bf(b1[(np * 16 + lhi * 4 + r) * 16 + n]);
    *(short4v*)(b1p + (size_t)((n * 16 + np) * 64 + lane) * 4) = b;
  }
}

// ---- K1: x -> g. 1024 WGs x 256 thr; WG = (n, rtg), wave wv = np-quarter. ----
__global__ __launch_bounds__(256, 4) void k1_gemm1(
    const float* __restrict__ x, const short* __restrict__ w1p,
    const short* __restrict__ b1p, short* __restrict__ G) {
  __shared__ __align__(16) short xs[128 * XPITCH];   // 18 KB staged slab (bf16)

  const int tid = threadIdx.x;
  const int wv = tid >> 6, lane = tid & 63;
  const int l15 = lane & 15, lhi = lane >> 4;
  const int b   = blockIdx.x;      // 0..1023
  const int n   = b >> 6;          // 0..15
  const int rtg = b & 63;          // rows rtg*128 .. +128
  const int np0 = wv * 4;

  // resident: 4 np of weights (32 VGPR) + bf16 bias (8 VGPR)
  short8  wf[4][2];
  short4v bv[4];
#pragma unroll
  for (int j = 0; j < 4; ++j) {
    const int np = np0 + j;
    wf[j][0] = *(const short8*)(w1p + (size_t)(((n * 16 + np) * 2 + 0) * 64 + lane) * 8);
    wf[j][1] = *(const short8*)(w1p + (size_t)(((n * 16 + np) * 2 + 1) * 64 + lane) * 8);
    bv[j]    = *(const short4v*)(b1p + (size_t)((n * 16 + np) * 64 + lane) * 4);
  }

  // ---- cooperative staging: 128 rows x 64 cols f32 -> bf16 LDS ----
  // pass p: thread handles row p*16 + (tid>>4), 4 floats at col (tid&15)*4.
  // Global: 16 lanes x 16B = 256B contiguous per row -> coalesced.
  {
    const int rr = tid >> 4;          // 0..15
    const int cc = (tid & 15) * 4;    // 0..60
    const float* px = x + (size_t)(rtg * 128 + rr) * 1024 + n * 64 + cc;
#pragma unroll
    for (int p = 0; p < 8; ++p) {
      floatx4 v = *(const floatx4*)(px + (size_t)p * 16 * 1024);
      short4v s;
#pragma unroll
      for (int e = 0; e < 4; ++e) s[e] = f2bf(v[e]);
      *(short4v*)(&xs[(p * 16 + rr) * XPITCH + cc]) = s;
    }
  }
  __syncthreads();

  // ---- 8 rowtiles: ds_read fragments, MFMA, gelu, contiguous stores ----
#pragma unroll
  for (int rt = 0; rt < 8; ++rt) {
    const short* xrow = &xs[(rt * 16 + l15) * XPITCH];
    short8 xf0 = *(const short8*)(xrow + lhi * 8);        // k = lhi*8+e
    short8 xf1 = *(const short8*)(xrow + 32 + lhi * 8);   // k = 32+lhi*8+e
    short* gb = G + (size_t)(rtg * 8 + rt) * 65536 + n * 256 + l15 * 16 + lhi * 4;
#pragma unroll
    for (int j = 0; j < 4; ++j) {
      floatx4 acc = {0.f, 0.f, 0.f, 0.f};
      acc = __builtin_amdgcn_mfma_f32_16x16x32_bf16(wf[j][0], xf0, acc, 0, 0, 0);
      acc = __builtin_amdgcn_mfma_f32_16x16x32_bf16(wf[j][1], xf1, acc, 0, 0, 0);
      short4v hv;
#pragma unroll
      for (int e = 0; e < 4; ++e)
        hv[e] = f2bf(gelu_f(acc[e] + bf2f(bv[j][e])));
      *(short4v*)(gb + (size_t)(np0 + j) * 4096) = hv;   // 512B/wave contiguous
    }
  }
}

// ---- K2: g -> y, 2048 WGs x 256 thr, wave = (rt, np)  [unchanged from R4] ----
__global__ __launch_bounds__(256, 4) void k2_gemm2(
    const short* __restrict__ G, const short* __restrict__ w2p,
    const float* __restrict__ b2, float* __restrict__ y) {
  const int tid = threadIdx.x;
  const int wv = tid >> 6, lane = tid & 63;
  const int l15 = lane & 15, lhi = lane >> 4;
  const int rt = blockIdx.x >> 2;
  const int np = (blockIdx.x & 3) * 4 + wv;

  const short* ab = G + (size_t)(rt * 16 + np) * 4096 + (lhi >> 1) * 256 + l15 * 16 + (lhi & 1) * 8;
  short8 af[8];
#pragma unroll
  for (int ks = 0; ks < 8; ++ks)
    af[ks] = *(const short8*)(ab + ks * 512);

#pragma unroll
  for (int ot = 0; ot < 4; ++ot) {
    floatx4 a0 = {0.f, 0.f, 0.f, 0.f}, a1 = {0.f, 0.f, 0.f, 0.f};
#pragma unroll
    for (int ks = 0; ks < 8; ks += 2) {
      short8 b0  = *(const short8*)(w2p + (size_t)(((np * 8 + ks) * 4 + ot) * 64 + lane) * 8);
      short8 b1f = *(const short8*)(w2p + (size_t)(((np * 8 + ks + 1) * 4 + ot) * 64 + lane) * 8);
      a0 = __builtin_amdgcn_mfma_f32_16x16x32_bf16(af[ks], b0, a0, 0, 0, 0);
      a1 = __builtin_amdgcn_mfma_f32_16x16x32_bf16(af[ks + 1], b1f, a1, 0, 0, 0);
    }
    const int col = np * 64 + ot * 16 + l15;
    const float bb = b2[col];
    float* py = y + (size_t)(rt * 16 + lhi * 4) * 1024 + col;
#pragma unroll
    for (int r = 0; r < 4; ++r)
      py[(size_t)r * 1024] = a0[r] + a1[r] + bb;
  }
}

extern "C" void kernel_launch(void* const* d_in, const int* in_sizes, int n_in,
                              void* d_out, int out_size, void* d_ws, size_t ws_size,
                              hipStream_t stream) {
  const float* x  = (const float*)d_in[0];
  const float* w1 = (const float*)d_in[1];
  const float* b1 = (const float*)d_in[2];
  const float* w2 = (const float*)d_in[3];
  const float* b2 = (const float*)d_in[4];
  float* y = (float*)d_out;

  short* w1p = (short*)d_ws;               // 512 KB
  short* w2p = w1p + 16 * 256 * 64;        // 512 KB
  short* b1p = w2p + 16 * 256 * 64;        // 128 KB
  short* G   = b1p + 16 * 16 * 64 * 4;     // 64 MB

  pack_k<<<160, 512, 0, stream>>>(w1, w2, b1, w1p, w2p, b1p);
  k1_gemm1<<<1024, 256, 0, stream>>>(x, w1p, b1p, G);
  k2_gemm2<<<2048, 256, 0, stream>>>(G, w2p, b2, y);
}

// Round 9
// 48.283 us; speedup vs baseline: 1.0812x; 1.0223x over previous
//
#include <hip/hip_runtime.h>
#include <hip/hip_bf16.h>

// ShuffleNet fused block-MLP, MI355X (gfx950).  R9: single fused kernel,
// one barrier total, wave-autonomous after x-staging.
// x:(8192,1024) f32; w1:(16,256,64); b1:(4096); w2:(16,64,256); b2:(1024); y f32.
//   h[b,n,o] = sum_i x[b,n*64+i]*w1[n,o,i];  shuffled j = o*16+n
//   g = gelu(h+b1);  y[b,np*64+o'] = sum_{i'} g[b,np*256+i']*w2[np,o',i'] + b2
//   i' = n*16 + ohi  with  o = np*16 + ohi.
// WG = 256 thr (4 waves) owns rowtile rt (16 rows) and an np-half (8 np).
// Stage x[rt*16..+16][0..1024) -> swizzled bf16 LDS (32 KB, coalesced), ONE
// __syncthreads, then each wave (2 np, sequential) runs with no barriers:
//   per np, 4 n-quarters: GEMM1 {ds_read xf, L2-stream w1 frags, 2 MFMA,
//   gelu x16, b64-write 2KB wave-private chunk}, then GEMM2 k-quarter
//   {2 ds_read af, L2-stream w2 frags, 8 MFMA into acc2}. y stored once.
// LDS 40 KB -> 4 WG/CU = 16 waves/CU; grid 1024 = exactly 4/CU, no tail.
// Swizzle: 8-short granule g -> g ^ (row&7) on both xs and chunk (b64/b128-safe).

typedef __attribute__((ext_vector_type(8))) short  short8;   // 8 bf16 = 4 VGPR
typedef __attribute__((ext_vector_type(4))) short  short4v;
typedef __attribute__((ext_vector_type(4))) float  floatx4;

__device__ __forceinline__ short f2bf(float f) {
  union { __hip_bfloat16 h; short s; } u;
  u.h = __float2bfloat16(f);
  return u.s;
}
__device__ __forceinline__ float bf2f(short s) {
  union { float f; unsigned u; } uu;
  uu.u = ((unsigned)(unsigned short)s) << 16;
  return uu.f;
}

// gelu(v) ~= v * sigmoid(1.5957691*(v + 0.044715 v^3)), exp2-folded:
// g = v * rcp(1 + exp2(v*(-2.3020807 - 0.1029375*v*v)))   (5 VALU + 2 TRANS)
__device__ __forceinline__ float gelu_f(float v) {
  float m = v * v;
  float c = fmaf(-0.1029375f, m, -2.3020807f);
  float z = v * c;
  float e = __builtin_amdgcn_exp2f(z);
  return v * __builtin_amdgcn_rcpf(1.0f + e);
}

// ---- pack kernel: w1 frags | w2 frags | b1 frags (bf16)  [as R8] ----
// w1 frag (n,np,ks): lane l elem e = w1[n][np*16+(l&15)][ks*32+(l>>4)*8+e]
// w2 frag (np,ks,ot): lane l elem e: k=ks*32+(l>>4)*8+e; value =
//                     w2[np][ot*16+(l&15)][(k&15)*16+(k>>4)]
// b1 frag (n,np): lane l reg r = bf16(b1[(np*16+(l>>4)*4+r)*16+n])
__global__ void pack_k(const float* __restrict__ w1, const float* __restrict__ w2,
                       const float* __restrict__ b1, short* __restrict__ w1p,
                       short* __restrict__ w2p, short* __restrict__ b1p) {
  const int t = blockIdx.x * blockDim.x + threadIdx.x;  // 160*512 = 81920
  const int lane = t & 63;
  const int lhi = lane >> 4;
  if (t < 32768) {  // w1
    const int ks = (t >> 6) & 1, np = (t >> 7) & 15, n = (t >> 11) & 15;
    const float* src = w1 + ((size_t)(n * 256 + np * 16 + (lane & 15)) * 64 + ks * 32 + lhi * 8);
    short8 f;
#pragma unroll
    for (int e = 0; e < 8; ++e) f[e] = f2bf(src[e]);
    *(short8*)(w1p + (size_t)t * 8) = f;
  } else if (t < 65536) {  // w2
    const int t2 = t - 32768;
    const int ot = (t2 >> 6) & 3, ks = (t2 >> 8) & 7, np = (t2 >> 11) & 15;
    const int op = ot * 16 + (lane & 15);
    short8 f;
#pragma unroll
    for (int e = 0; e < 8; ++e) {
      const int k = ks * 32 + lhi * 8 + e;
      f[e] = f2bf(w2[(size_t)(np * 64 + op) * 256 + (k & 15) * 16 + (k >> 4)]);
    }
    *(short8*)(w2p + (size_t)t2 * 8) = f;
  } else {  // b1 -> bf16 frags
    const int t3 = t - 65536;  // 16384
    const int np = (t3 >> 6) & 15, n = (t3 >> 10) & 15;
    short4v b;
#pragma unroll
    for (int r = 0; r < 4; ++r) b[r] = f2bf(b1[(np * 16 + lhi * 4 + r) * 16 + n]);
    *(short4v*)(b1p + (size_t)((n * 16 + np) * 64 + lane) * 4) = b;
  }
}

// ---- fused: 1024 WGs x 256 thr; WG = (rt = b>>1, np-half = b&1) ----
__global__ __launch_bounds__(256, 4) void fused_k(
    const float* __restrict__ x, const short* __restrict__ w1p,
    const short* __restrict__ w2p, const short* __restrict__ b1p,
    const float* __restrict__ b2, float* __restrict__ y) {
  __shared__ __align__(16) short xs[16 * 1024];   // 32 KB staged x (swizzled)
  __shared__ __align__(16) short ch[4 * 16 * 64]; // 8 KB: per-wave 2KB chunk qtr

  const int tid = threadIdx.x;
  const int wv = tid >> 6, lane = tid & 63;
  const int l15 = lane & 15, lhi = lane >> 4;
  const int rt  = blockIdx.x >> 1;
  const int nph = blockIdx.x & 1;

  // ---- stage: 16 rows x 1024 f32 -> bf16 swizzled LDS (coalesced 1KB/inst) ----
#pragma unroll
  for (int p = 0; p < 4; ++p) {
    const int row = wv * 4 + p;
    const int rsw = (row & 7) << 3;
#pragma unroll
    for (int q = 0; q < 4; ++q) {
      const int col = q * 256 + lane * 4;
      floatx4 v = *(const floatx4*)(x + (size_t)(rt * 16 + row) * 1024 + col);
      short4v s;
#pragma unroll
      for (int e = 0; e < 4; ++e) s[e] = f2bf(v[e]);
      *(short4v*)(&xs[row * 1024 + (col ^ rsw)]) = s;
    }
  }
  __syncthreads();   // the only barrier

  const int swz = (l15 & 7) << 3;        // read/write swizzle for row l15
  short* myc = ch + wv * 1024;           // wave-private 16x64 chunk quarter

#pragma unroll
  for (int it = 0; it < 2; ++it) {
    const int np = nph * 8 + wv * 2 + it;
    floatx4 acc2[4] = {{0.f,0.f,0.f,0.f},{0.f,0.f,0.f,0.f},
                       {0.f,0.f,0.f,0.f},{0.f,0.f,0.f,0.f}};

#pragma unroll
    for (int h = 0; h < 4; ++h) {        // n-quarter / k-quarter
      // -- GEMM1 for n = 4h..4h+3: chunk cols (n&3)*16+ohi --
#pragma unroll
      for (int nn = 0; nn < 4; ++nn) {
        const int n = h * 4 + nn;
        short8 xf0 = *(const short8*)(&xs[l15 * 1024 + ((n * 64 + lhi * 8) ^ swz)]);
        short8 xf1 = *(const short8*)(&xs[l15 * 1024 + ((n * 64 + 32 + lhi * 8) ^ swz)]);
        short8 wf0 = *(const short8*)(w1p + (size_t)(((n * 16 + np) * 2 + 0) * 64 + lane) * 8);
        short8 wf1 = *(const short8*)(w1p + (size_t)(((n * 16 + np) * 2 + 1) * 64 + lane) * 8);
        short4v bv = *(const short4v*)(b1p + (size_t)((n * 16 + np) * 64 + lane) * 4);
        floatx4 acc = {0.f, 0.f, 0.f, 0.f};
        acc = __builtin_amdgcn_mfma_f32_16x16x32_bf16(wf0, xf0, acc, 0, 0, 0);
        acc = __builtin_amdgcn_mfma_f32_16x16x32_bf16(wf1, xf1, acc, 0, 0, 0);
        short4v hv;
#pragma unroll
        for (int e = 0; e < 4; ++e)
          hv[e] = f2bf(gelu_f(acc[e] + bf2f(bv[e])));
        *(short4v*)(&myc[l15 * 64 + ((nn * 16 + lhi * 4) ^ swz)]) = hv;
      }
      // -- GEMM2 k-quarter: ks = 2h, 2h+1 (same-wave LDS RAW, no barrier) --
      short8 af0 = *(const short8*)(&myc[l15 * 64 + ((0 * 32 + lhi * 8) ^ swz)]);
      short8 af1 = *(const short8*)(&myc[l15 * 64 + ((1 * 32 + lhi * 8) ^ swz)]);
#pragma unroll
      for (int ot = 0; ot < 4; ++ot) {
        short8 bf0 = *(const short8*)(w2p + (size_t)(((np * 8 + 2 * h) * 4 + ot) * 64 + lane) * 8);
        short8 bf1 = *(const short8*)(w2p + (size_t)(((np * 8 + 2 * h + 1) * 4 + ot) * 64 + lane) * 8);
        acc2[ot] = __builtin_amdgcn_mfma_f32_16x16x32_bf16(af0, bf0, acc2[ot], 0, 0, 0);
        acc2[ot] = __builtin_amdgcn_mfma_f32_16x16x32_bf16(af1, bf1, acc2[ot], 0, 0, 0);
      }
    }

    // -- y store: col = np*64 + ot*16 + l15, rows rt*16 + lhi*4 + r --
#pragma unroll
    for (int ot = 0; ot < 4; ++ot) {
      const int col = np * 64 + ot * 16 + l15;
      const float bb = b2[col];
      float* py = y + (size_t)(rt * 16 + lhi * 4) * 1024 + col;
#pragma unroll
      for (int r = 0; r < 4; ++r)
        py[(size_t)r * 1024] = acc2[ot][r] + bb;
    }
  }
}

extern "C" void kernel_launch(void* const* d_in, const int* in_sizes, int n_in,
                              void* d_out, int out_size, void* d_ws, size_t ws_size,
                              hipStream_t stream) {
  const float* x  = (const float*)d_in[0];
  const float* w1 = (const float*)d_in[1];
  const float* b1 = (const float*)d_in[2];
  const float* w2 = (const float*)d_in[3];
  const float* b2 = (const float*)d_in[4];
  float* y = (float*)d_out;

  short* w1p = (short*)d_ws;               // 512 KB
  short* w2p = w1p + 16 * 256 * 64;        // 512 KB
  short* b1p = w2p + 16 * 256 * 64;        // 128 KB

  pack_k<<<160, 512, 0, stream>>>(w1, w2, b1, w1p, w2p, b1p);
  fused_k<<<1024, 256, 0, stream>>>(x, w1p, w2p, b1p, b2, y);
}

// Round 11
// 47.494 us; speedup vs baseline: 1.0992x; 1.0166x over previous
//
#include <hip/hip_runtime.h>
#include <hip/hip_bf16.h>

// ShuffleNet fused block-MLP, MI355X (gfx950).  R11: the channel shuffle is
// absorbed into a k-axis permutation of the w2 pre-pack (MFMA contraction is
// permutation-invariant), so GEMM1->GEMM2 handoff is REGISTER-LOCAL: zero
// LDS chunk, zero cross-lane ops.
// x:(8192,1024) f32; w1:(16,256,64); b1:(4096); w2:(16,64,256); b2:(1024); y f32.
//   h[b,n,o] = sum_i x[b,n*64+i]*w1[n,o,i];  shuffled j = o*16+n
//   g = gelu(h+b1);  y[b,np*64+o'] = sum_{K} g[b,np*256+K]*w2'[np,o',K] + b2
//   chunk index K = n*16 + ohi, o = np*16 + ohi; w2'[..][K] = w2[..][ohi*16+n].
// k-permutation pi folded into w2 pack:  pi(k) = 32*(k>>5) + 16*((k>>2)&1)
//   + 4*((k>>3)&3) + (k&3)   (bijection; applied to A implicitly, B at pack).
// With pi, GEMM2 A-frag for slice s = {pk[2s][0],pk[2s][1],pk[2s+1][0],
//   pk[2s+1][1]} of the SAME lane (pk[n][c] = packed gelu output regs 2c,2c+1).
// fused: 2048 WGs x 256 thr; WG = (rt = b>>2, npq = b&3); wave np = npq*4+wv.
// x staged once per WG to LDS (pitch 1032 shorts -> b128 reads exactly
// 8 dwords/bank, conflict-free); one barrier total.

typedef __attribute__((ext_vector_type(8))) short  short8;   // 8 bf16 = 4 VGPR
typedef __attribute__((ext_vector_type(4))) short  short4v;
typedef __attribute__((ext_vector_type(4))) float  floatx4;

#define XP 1032   // xs row pitch in shorts (516 dw = 4 mod 32 -> bank rotation)

__device__ __forceinline__ short f2bf(float f) {
  union { __hip_bfloat16 h; short s; } u;
  u.h = __float2bfloat16(f);
  return u.s;
}
__device__ __forceinline__ float bf2f(short s) {
  union { float f; unsigned u; } uu;
  uu.u = ((unsigned)(unsigned short)s) << 16;
  return uu.f;
}
__device__ __forceinline__ int pk16(float a, float b) {
  return (int)(unsigned short)f2bf(a) | ((int)(unsigned short)f2bf(b) << 16);
}

// gelu(v) ~= v * sigmoid(1.5957691*(v + 0.044715 v^3)), exp2-folded (abs<5e-4)
__device__ __forceinline__ float gelu_f(float v) {
  float m = v * v;
  float c = fmaf(-0.1029375f, m, -2.3020807f);
  float z = v * c;
  float e = __builtin_amdgcn_exp2f(z);
  return v * __builtin_amdgcn_rcpf(1.0f + e);
}

// ---- pack kernel: w1 frags | w2 frags (pi-permuted) | b1 frags (bf16) ----
__global__ void pack_k(const float* __restrict__ w1, const float* __restrict__ w2,
                       const float* __restrict__ b1, short* __restrict__ w1p,
                       short* __restrict__ w2p, short* __restrict__ b1p) {
  const int t = blockIdx.x * blockDim.x + threadIdx.x;  // 160*512 = 81920
  const int lane = t & 63;
  const int lhi = lane >> 4;
  if (t < 32768) {  // w1 frag (n,np,ks): lane l elem e = w1[n][np*16+(l&15)][ks*32+lhi*8+e]
    const int ks = (t >> 6) & 1, np = (t >> 7) & 15, n = (t >> 11) & 15;
    const float* src = w1 + ((size_t)(n * 256 + np * 16 + (lane & 15)) * 64 + ks * 32 + lhi * 8);
    short8 f;
#pragma unroll
    for (int e = 0; e < 8; ++e) f[e] = f2bf(src[e]);
    *(short8*)(w1p + (size_t)t * 8) = f;
  } else if (t < 65536) {  // w2 frag (np,s,ot), pi-permuted k
    const int t2 = t - 32768;
    const int ot = (t2 >> 6) & 3, s = (t2 >> 8) & 7, np = (t2 >> 11) & 15;
    const int op = ot * 16 + (lane & 15);
    short8 f;
#pragma unroll
    for (int e = 0; e < 8; ++e) {
      // physical k = s*32 + lhi*8 + e ; chunk index Kc = pi(k):
      const int Kc = 32 * s + 16 * ((e >> 2) & 1) + 4 * lhi + (e & 3);
      const int n = Kc >> 4, ohi = Kc & 15;
      f[e] = f2bf(w2[(size_t)(np * 64 + op) * 256 + ohi * 16 + n]);
    }
    *(short8*)(w2p + (size_t)t2 * 8) = f;
  } else {  // b1 frag (n,np): lane l reg r = bf16(b1[(np*16+lhi*4+r)*16+n])
    const int t3 = t - 65536;  // 16384
    const int np = (t3 >> 6) & 15, n = (t3 >> 10) & 15;
    short4v b;
#pragma unroll
    for (int r = 0; r < 4; ++r) b[r] = f2bf(b1[(np * 16 + lhi * 4 + r) * 16 + n]);
    *(short4v*)(b1p + (size_t)((n * 16 + np) * 64 + lane) * 4) = b;
  }
}

// ---- fused: 2048 WGs x 256 thr; WG = (rt, npq); wave np = npq*4 + wv ----
__global__ __launch_bounds__(256, 4) void fused_k(
    const float* __restrict__ x, const short* __restrict__ w1p,
    const short* __restrict__ w2p, const short* __restrict__ b1p,
    const float* __restrict__ b2, float* __restrict__ y) {
  __shared__ __align__(16) short xs[16 * XP];   // 33 KB staged x

  const int tid = threadIdx.x;
  const int wv = tid >> 6, lane = tid & 63;
  const int l15 = lane & 15, lhi = lane >> 4;
  const int rt  = blockIdx.x >> 2;
  const int np  = (blockIdx.x & 3) * 4 + wv;

  // ---- stage: 16 rows x 1024 f32 -> bf16 LDS (1KB contiguous per inst) ----
#pragma unroll
  for (int p = 0; p < 4; ++p) {
    const int row = wv * 4 + p;
#pragma unroll
    for (int q = 0; q < 4; ++q) {
      const int col = q * 256 + lane * 4;
      floatx4 v = *(const floatx4*)(x + (size_t)(rt * 16 + row) * 1024 + col);
      short4v sv;
#pragma unroll
      for (int e = 0; e < 4; ++e) sv[e] = f2bf(v[e]);
      *(short4v*)(&xs[row * XP + col]) = sv;
    }
  }
  __syncthreads();   // the only barrier

  floatx4 c0 = {0.f,0.f,0.f,0.f}, c1 = {0.f,0.f,0.f,0.f};
  floatx4 c2 = {0.f,0.f,0.f,0.f}, c3 = {0.f,0.f,0.f,0.f};

#pragma unroll
  for (int s = 0; s < 8; ++s) {
    int pka0, pka1, pkb0, pkb1;   // pk[2s][0..1], pk[2s+1][0..1]

    // ---- GEMM1 block n = 2s ----
    {
      const int n = 2 * s;
      short8 xf0 = *(const short8*)(&xs[l15 * XP + n * 64 + lhi * 8]);
      short8 xf1 = *(const short8*)(&xs[l15 * XP + n * 64 + 32 + lhi * 8]);
      short8 wf0 = *(const short8*)(w1p + (size_t)(((n * 16 + np) * 2 + 0) * 64 + lane) * 8);
      short8 wf1 = *(const short8*)(w1p + (size_t)(((n * 16 + np) * 2 + 1) * 64 + lane) * 8);
      short4v bv = *(const short4v*)(b1p + (size_t)((n * 16 + np) * 64 + lane) * 4);
      floatx4 acc = {0.f, 0.f, 0.f, 0.f};
      acc = __builtin_amdgcn_mfma_f32_16x16x32_bf16(wf0, xf0, acc, 0, 0, 0);
      acc = __builtin_amdgcn_mfma_f32_16x16x32_bf16(wf1, xf1, acc, 0, 0, 0);
      const float g0 = gelu_f(acc[0] + bf2f(bv[0]));
      const float g1 = gelu_f(acc[1] + bf2f(bv[1]));
      const float g2 = gelu_f(acc[2] + bf2f(bv[2]));
      const float g3 = gelu_f(acc[3] + bf2f(bv[3]));
      pka0 = pk16(g0, g1);
      pka1 = pk16(g2, g3);
    }
    // ---- GEMM1 block n = 2s+1 ----
    {
      const int n = 2 * s + 1;
      short8 xf0 = *(const short8*)(&xs[l15 * XP + n * 64 + lhi * 8]);
      short8 xf1 = *(const short8*)(&xs[l15 * XP + n * 64 + 32 + lhi * 8]);
      short8 wf0 = *(const short8*)(w1p + (size_t)(((n * 16 + np) * 2 + 0) * 64 + lane) * 8);
      short8 wf1 = *(const short8*)(w1p + (size_t)(((n * 16 + np) * 2 + 1) * 64 + lane) * 8);
      short4v bv = *(const short4v*)(b1p + (size_t)((n * 16 + np) * 64 + lane) * 4);
      floatx4 acc = {0.f, 0.f, 0.f, 0.f};
      acc = __builtin_amdgcn_mfma_f32_16x16x32_bf16(wf0, xf0, acc, 0, 0, 0);
      acc = __builtin_amdgcn_mfma_f32_16x16x32_bf16(wf1, xf1, acc, 0, 0, 0);
      const float g0 = gelu_f(acc[0] + bf2f(bv[0]));
      const float g1 = gelu_f(acc[1] + bf2f(bv[1]));
      const float g2 = gelu_f(acc[2] + bf2f(bv[2]));
      const float g3 = gelu_f(acc[3] + bf2f(bv[3]));
      pkb0 = pk16(g0, g1);
      pkb1 = pk16(g2, g3);
    }

    // ---- GEMM2 slice s: A-frag is this lane's own registers ----
    union { int i[4]; short8 v; } af;
    af.i[0] = pka0; af.i[1] = pka1; af.i[2] = pkb0; af.i[3] = pkb1;
    const size_t wb = (size_t)((np * 8 + s) * 4) * 64 * 8;
    short8 bf0 = *(const short8*)(w2p + wb + (size_t)(0 * 64 + lane) * 8);
    short8 bf1 = *(const short8*)(w2p + wb + (size_t)(1 * 64 + lane) * 8);
    short8 bf2v = *(const short8*)(w2p + wb + (size_t)(2 * 64 + lane) * 8);
    short8 bf3 = *(const short8*)(w2p + wb + (size_t)(3 * 64 + lane) * 8);
    c0 = __builtin_amdgcn_mfma_f32_16x16x32_bf16(af.v, bf0, c0, 0, 0, 0);
    c1 = __builtin_amdgcn_mfma_f32_16x16x32_bf16(af.v, bf1, c1, 0, 0, 0);
    c2 = __builtin_amdgcn_mfma_f32_16x16x32_bf16(af.v, bf2v, c2, 0, 0, 0);
    c3 = __builtin_amdgcn_mfma_f32_16x16x32_bf16(af.v, bf3, c3, 0, 0, 0);
  }

  // ---- y store: col = np*64 + ot*16 + l15, rows rt*16 + lhi*4 + r ----
  floatx4 cc[4] = {c0, c1, c2, c3};
#pragma unroll
  for (int ot = 0; ot < 4; ++ot) {
    const int col = np * 64 + ot * 16 + l15;
    const float bb = b2[col];
    float* py = y + (size_t)(rt * 16 + lhi * 4) * 1024 + col;
#pragma unroll
    for (int r = 0; r < 4; ++r)
      py[(size_t)r * 1024] = cc[ot][r] + bb;
  }
}

extern "C" void kernel_launch(void* const* d_in, const int* in_sizes, int n_in,
                              void* d_out, int out_size, void* d_ws, size_t ws_size,
                              hipStream_t stream) {
  const float* x  = (const float*)d_in[0];
  const float* w1 = (const float*)d_in[1];
  const float* b1 = (const float*)d_in[2];
  const float* w2 = (const float*)d_in[3];
  const float* b2 = (const float*)d_in[4];
  float* y = (float*)d_out;

  short* w1p = (short*)d_ws;               // 512 KB
  short* w2p = w1p + 16 * 256 * 64;        // 512 KB
  short* b1p = w2p + 16 * 256 * 64;        // 128 KB

  pack_k<<<160, 512, 0, stream>>>(w1, w2, b1, w1p, w2p, b1p);
  fused_k<<<2048, 256, 0, stream>>>(x, w1p, w2p, b1p, b2, y);
}